// Round 1
// baseline (327.512 us; speedup 1.0000x reference)
//
#include <hip/hip_runtime.h>
#include <hip/hip_bf16.h>

#define BN_EPS 1e-5f

// ---------------------------------------------------------------------------
// K1: per-edge dot product likelihood[e] = <src_emb[gsrc[e]], dst_emb[gdst[e]]>
//     + block-reduced sum / sum-of-squares into double accumulators.
// Embedding rows are 12 floats = 48 B, and 48 % 16 == 0, so float4 loads are
// always 16B-aligned.
// ---------------------------------------------------------------------------
__global__ void k_dot_stats(const float* __restrict__ src_emb,
                            const float* __restrict__ dst_emb,
                            const int* __restrict__ gsrc,
                            const int* __restrict__ gdst,
                            float* __restrict__ like,
                            double* __restrict__ acc,   // acc[0]=sum, acc[1]=sumsq
                            int E) {
    float lsum = 0.f, lsq = 0.f;
    for (int e = blockIdx.x * blockDim.x + threadIdx.x; e < E;
         e += gridDim.x * blockDim.x) {
        int s = gsrc[e];
        int d = gdst[e];
        const float4* a = (const float4*)(src_emb + (size_t)s * 12);
        const float4* b = (const float4*)(dst_emb + (size_t)d * 12);
        float4 a0 = a[0], a1 = a[1], a2 = a[2];
        float4 b0 = b[0], b1 = b[1], b2 = b[2];
        float dot = a0.x * b0.x + a0.y * b0.y + a0.z * b0.z + a0.w * b0.w
                  + a1.x * b1.x + a1.y * b1.y + a1.z * b1.z + a1.w * b1.w
                  + a2.x * b2.x + a2.y * b2.y + a2.z * b2.z + a2.w * b2.w;
        like[e] = dot;
        lsum += dot;
        lsq  += dot * dot;
    }
    // wave (64-lane) shuffle reduction
    for (int off = 32; off > 0; off >>= 1) {
        lsum += __shfl_down(lsum, off);
        lsq  += __shfl_down(lsq, off);
    }
    __shared__ float ssum[8], ssq[8];   // up to 8 waves per 512-thread block
    int wave = threadIdx.x >> 6;
    int lane = threadIdx.x & 63;
    if (lane == 0) { ssum[wave] = lsum; ssq[wave] = lsq; }
    __syncthreads();
    if (threadIdx.x == 0) {
        float ts = 0.f, tq = 0.f;
        int nw = blockDim.x >> 6;
        for (int i = 0; i < nw; ++i) { ts += ssum[i]; tq += ssq[i]; }
        atomicAdd(&acc[0], (double)ts);
        atomicAdd(&acc[1], (double)tq);
    }
}

// ---------------------------------------------------------------------------
// K2: fold batch stats + bn affine into a single (scale, shift) pair.
// logits = (x - mean) * rsqrt(var+eps) * w + b  ==  x*scale + shift
// ---------------------------------------------------------------------------
__global__ void k_params(const double* __restrict__ acc,
                         const float* __restrict__ bnw,
                         const float* __restrict__ bnb,
                         float* __restrict__ params,
                         int E) {
    double mean = acc[0] / (double)E;
    double var  = acc[1] / (double)E - mean * mean;
    float invstd = rsqrtf((float)var + BN_EPS);
    float scale = bnw[0] * invstd;
    params[0] = scale;
    params[1] = bnb[0] - (float)mean * scale;
}

// ---------------------------------------------------------------------------
// K3: w[e] = exp(like[e]*scale + shift) (in-place over `like`),
//     denom[gsrc[e]] += w[e]  (float atomics, ~32 collisions/node avg)
// ---------------------------------------------------------------------------
__global__ void k_exp_scatter(float* __restrict__ w,          // in: like, out: exp
                              const int* __restrict__ gsrc,
                              const float* __restrict__ params,
                              float* __restrict__ denom,
                              int E) {
    float scale = params[0];
    float shift = params[1];
    for (int e = blockIdx.x * blockDim.x + threadIdx.x; e < E;
         e += gridDim.x * blockDim.x) {
        float v = __expf(fmaf(w[e], scale, shift));
        w[e] = v;
        atomicAdd(&denom[gsrc[e]], v);
    }
}

// ---------------------------------------------------------------------------
// K4: out[e] = w[e] / (1e-12 + denom[gsrc[e]])
// ---------------------------------------------------------------------------
__global__ void k_normalize(const float* __restrict__ w,
                            const int* __restrict__ gsrc,
                            const float* __restrict__ denom,
                            float* __restrict__ out,
                            int E) {
    for (int e = blockIdx.x * blockDim.x + threadIdx.x; e < E;
         e += gridDim.x * blockDim.x) {
        out[e] = w[e] / (1e-12f + denom[gsrc[e]]);
    }
}

extern "C" void kernel_launch(void* const* d_in, const int* in_sizes, int n_in,
                              void* d_out, int out_size, void* d_ws, size_t ws_size,
                              hipStream_t stream) {
    const float* src_emb = (const float*)d_in[0];
    const float* dst_emb = (const float*)d_in[1];
    const float* bnw     = (const float*)d_in[2];
    const float* bnb     = (const float*)d_in[3];
    const int*   gsrc    = (const int*)d_in[4];
    const int*   gdst    = (const int*)d_in[5];

    const int E = in_sizes[4];           // 3,200,000 edges
    const int N = in_sizes[0] / 12;      // 100,000 nodes
    float* out = (float*)d_out;

    // workspace layout
    char* ws = (char*)d_ws;
    double* acc   = (double*)ws;                          // 16 B
    float* params = (float*)(ws + 16);                    // 8 B (padded to 32)
    float* like   = (float*)(ws + 32);                    // E floats (reused as w)
    float* denom  = (float*)(ws + 32 + (size_t)E * 4);    // N floats

    // zero the accumulators and segment-sum buffer every call (harness does
    // not re-poison/zero between replays)
    hipMemsetAsync(ws, 0, 32, stream);
    hipMemsetAsync(denom, 0, (size_t)N * 4, stream);

    const int block = 256;
    const int blocks = min((E + block - 1) / block, 4096);

    k_dot_stats<<<blocks, block, 0, stream>>>(src_emb, dst_emb, gsrc, gdst,
                                              like, acc, E);
    k_params<<<1, 1, 0, stream>>>(acc, bnw, bnb, params, E);
    k_exp_scatter<<<blocks, block, 0, stream>>>(like, gsrc, params, denom, E);
    k_normalize<<<blocks, block, 0, stream>>>(like, gsrc, denom, out, E);
}

// Round 2
// 327.378 us; speedup vs baseline: 1.0004x; 1.0004x over previous
//
#include <hip/hip_runtime.h>
#include <hip/hip_bf16.h>

#define BN_EPS 1e-5f

// ---------------------------------------------------------------------------
// K1: per-edge dot product likelihood[e] = <src_emb[gsrc[e]], dst_emb[gdst[e]]>
//     + block-reduced sum / sum-of-squares into double accumulators.
// ---------------------------------------------------------------------------
__global__ void k_dot_stats(const float* __restrict__ src_emb,
                            const float* __restrict__ dst_emb,
                            const int* __restrict__ gsrc,
                            const int* __restrict__ gdst,
                            float* __restrict__ like,
                            double* __restrict__ acc,   // acc[0]=sum, acc[1]=sumsq
                            int E) {
    float lsum = 0.f, lsq = 0.f;
    for (int e = blockIdx.x * blockDim.x + threadIdx.x; e < E;
         e += gridDim.x * blockDim.x) {
        int s = gsrc[e];
        int d = gdst[e];
        const float4* a = (const float4*)(src_emb + (size_t)s * 12);
        const float4* b = (const float4*)(dst_emb + (size_t)d * 12);
        float4 a0 = a[0], a1 = a[1], a2 = a[2];
        float4 b0 = b[0], b1 = b[1], b2 = b[2];
        float dot = a0.x * b0.x + a0.y * b0.y + a0.z * b0.z + a0.w * b0.w
                  + a1.x * b1.x + a1.y * b1.y + a1.z * b1.z + a1.w * b1.w
                  + a2.x * b2.x + a2.y * b2.y + a2.z * b2.z + a2.w * b2.w;
        like[e] = dot;
        lsum += dot;
        lsq  += dot * dot;
    }
    for (int off = 32; off > 0; off >>= 1) {
        lsum += __shfl_down(lsum, off);
        lsq  += __shfl_down(lsq, off);
    }
    __shared__ float ssum[8], ssq[8];
    int wave = threadIdx.x >> 6;
    int lane = threadIdx.x & 63;
    if (lane == 0) { ssum[wave] = lsum; ssq[wave] = lsq; }
    __syncthreads();
    if (threadIdx.x == 0) {
        float ts = 0.f, tq = 0.f;
        int nw = blockDim.x >> 6;
        for (int i = 0; i < nw; ++i) { ts += ssum[i]; tq += ssq[i]; }
        atomicAdd(&acc[0], (double)ts);
        atomicAdd(&acc[1], (double)tq);
    }
}

// ---------------------------------------------------------------------------
// K2: fold batch stats + bn affine into (scale, shift).
// ---------------------------------------------------------------------------
__global__ void k_params(const double* __restrict__ acc,
                         const float* __restrict__ bnw,
                         const float* __restrict__ bnb,
                         float* __restrict__ params,
                         int E) {
    double mean = acc[0] / (double)E;
    double var  = acc[1] / (double)E - mean * mean;
    float invstd = rsqrtf((float)var + BN_EPS);
    float scale = bnw[0] * invstd;
    params[0] = scale;
    params[1] = bnb[0] - (float)mean * scale;
}

// ---------------------------------------------------------------------------
// K3: w[e] = exp(like[e]*scale + shift) in-place; scatter into REPLICATED
// denominator arrays denomR[r][node] (r = blockIdx & Rmask) to cut
// same-address / same-cache-line contention at the far-atomic point.
// ---------------------------------------------------------------------------
__global__ void k_exp_scatter(float* __restrict__ w,
                              const int* __restrict__ gsrc,
                              const float* __restrict__ params,
                              float* __restrict__ denomR,
                              int N, int Rmask, int E) {
    float scale = params[0];
    float shift = params[1];
    float* dr = denomR + (size_t)(blockIdx.x & Rmask) * N;
    for (int e = blockIdx.x * blockDim.x + threadIdx.x; e < E;
         e += gridDim.x * blockDim.x) {
        float v = __expf(fmaf(w[e], scale, shift));
        w[e] = v;
        atomicAdd(&dr[gsrc[e]], v);
    }
}

// ---------------------------------------------------------------------------
// K3b: fold replicas: denom[n] = sum_r denomR[r][n]
// ---------------------------------------------------------------------------
__global__ void k_fold(const float* __restrict__ denomR,
                       float* __restrict__ denom, int N, int R) {
    int n = blockIdx.x * blockDim.x + threadIdx.x;
    if (n < N) {
        float s = 0.f;
        for (int r = 0; r < R; ++r) s += denomR[(size_t)r * N + n];
        denom[n] = s;
    }
}

// ---------------------------------------------------------------------------
// K4: out[e] = w[e] / (1e-12 + denom[gsrc[e]])
// ---------------------------------------------------------------------------
__global__ void k_normalize(const float* __restrict__ w,
                            const int* __restrict__ gsrc,
                            const float* __restrict__ denom,
                            float* __restrict__ out,
                            int E) {
    for (int e = blockIdx.x * blockDim.x + threadIdx.x; e < E;
         e += gridDim.x * blockDim.x) {
        out[e] = w[e] / (1e-12f + denom[gsrc[e]]);
    }
}

extern "C" void kernel_launch(void* const* d_in, const int* in_sizes, int n_in,
                              void* d_out, int out_size, void* d_ws, size_t ws_size,
                              hipStream_t stream) {
    const float* src_emb = (const float*)d_in[0];
    const float* dst_emb = (const float*)d_in[1];
    const float* bnw     = (const float*)d_in[2];
    const float* bnb     = (const float*)d_in[3];
    const int*   gsrc    = (const int*)d_in[4];
    const int*   gdst    = (const int*)d_in[5];

    const int E = in_sizes[4];           // 3,200,000 edges
    const int N = in_sizes[0] / 12;      // 100,000 nodes
    float* out = (float*)d_out;

    // workspace layout:
    //   [0,16)          double acc[2]
    //   [16,32)         float params[2]
    //   [32, 32+4E)     like / w
    //   then            denom fold target (N floats)
    //   then            denomR (R * N floats), R = pow2 fitting in ws
    char* ws = (char*)d_ws;
    double* acc    = (double*)ws;
    float*  params = (float*)(ws + 16);
    float*  like   = (float*)(ws + 32);
    float*  denom  = (float*)(ws + 32 + (size_t)E * 4);
    float*  denomR = denom + N;

    size_t base = 32 + (size_t)E * 4 + (size_t)N * 4;
    int R = 1;
    while (R < 16 && base + (size_t)(R * 2) * N * 4 <= ws_size) R *= 2;
    int Rmask = R - 1;

    hipMemsetAsync(ws, 0, 32, stream);
    hipMemsetAsync(denomR, 0, (size_t)R * N * 4, stream);

    const int block = 256;
    const int blocks = min((E + block - 1) / block, 4096);

    k_dot_stats<<<blocks, block, 0, stream>>>(src_emb, dst_emb, gsrc, gdst,
                                              like, acc, E);
    k_params<<<1, 1, 0, stream>>>(acc, bnw, bnb, params, E);
    k_exp_scatter<<<blocks, block, 0, stream>>>(like, gsrc, params, denomR,
                                                N, Rmask, E);
    k_fold<<<(N + block - 1) / block, block, 0, stream>>>(denomR, denom, N, R);
    k_normalize<<<blocks, block, 0, stream>>>(like, gsrc, denom, out, E);
}

// Round 3
// 322.472 us; speedup vs baseline: 1.0156x; 1.0152x over previous
//
#include <hip/hip_runtime.h>
#include <hip/hip_bf16.h>

#define BN_EPS 1e-5f
#define NUM_XCD 8

__device__ __forceinline__ int xcc_id() {
    int x;
    asm volatile("s_getreg_b32 %0, hwreg(HW_REG_XCC_ID)" : "=s"(x));
    return x & (NUM_XCD - 1);
}

// ---------------------------------------------------------------------------
// K1: per-edge dot product + block-reduced sum/sumsq into double accumulators.
// ---------------------------------------------------------------------------
__global__ void k_dot_stats(const float* __restrict__ src_emb,
                            const float* __restrict__ dst_emb,
                            const int* __restrict__ gsrc,
                            const int* __restrict__ gdst,
                            float* __restrict__ like,
                            double* __restrict__ acc,   // acc[0]=sum, acc[1]=sumsq
                            int E) {
    float lsum = 0.f, lsq = 0.f;
    for (int e = blockIdx.x * blockDim.x + threadIdx.x; e < E;
         e += gridDim.x * blockDim.x) {
        int s = gsrc[e];
        int d = gdst[e];
        const float4* a = (const float4*)(src_emb + (size_t)s * 12);
        const float4* b = (const float4*)(dst_emb + (size_t)d * 12);
        float4 a0 = a[0], a1 = a[1], a2 = a[2];
        float4 b0 = b[0], b1 = b[1], b2 = b[2];
        float dot = a0.x * b0.x + a0.y * b0.y + a0.z * b0.z + a0.w * b0.w
                  + a1.x * b1.x + a1.y * b1.y + a1.z * b1.z + a1.w * b1.w
                  + a2.x * b2.x + a2.y * b2.y + a2.z * b2.z + a2.w * b2.w;
        like[e] = dot;
        lsum += dot;
        lsq  += dot * dot;
    }
    for (int off = 32; off > 0; off >>= 1) {
        lsum += __shfl_down(lsum, off);
        lsq  += __shfl_down(lsq, off);
    }
    __shared__ float ssum[8], ssq[8];
    int wave = threadIdx.x >> 6;
    int lane = threadIdx.x & 63;
    if (lane == 0) { ssum[wave] = lsum; ssq[wave] = lsq; }
    __syncthreads();
    if (threadIdx.x == 0) {
        float ts = 0.f, tq = 0.f;
        int nw = blockDim.x >> 6;
        for (int i = 0; i < nw; ++i) { ts += ssum[i]; tq += ssq[i]; }
        atomicAdd(&acc[0], (double)ts);
        atomicAdd(&acc[1], (double)tq);
    }
}

// ---------------------------------------------------------------------------
// K2: fold batch stats + bn affine into (scale, shift).
// ---------------------------------------------------------------------------
__global__ void k_params(const double* __restrict__ acc,
                         const float* __restrict__ bnw,
                         const float* __restrict__ bnb,
                         float* __restrict__ params,
                         int E) {
    double mean = acc[0] / (double)E;
    double var  = acc[1] / (double)E - mean * mean;
    float invstd = rsqrtf((float)var + BN_EPS);
    float scale = bnw[0] * invstd;
    params[0] = scale;
    params[1] = bnb[0] - (float)mean * scale;
}

// ---------------------------------------------------------------------------
// K3 (XCD-local): w[e] = exp(like*scale+shift) in-place; scatter into the
// replica owned by THIS XCD with a WORKGROUP-scope atomic. Since only blocks
// on XCD x ever touch denomR[x], the atomic can legally execute in the local
// XCD's L2 (which serializes all CUs on that XCD) instead of going to the
// memory-side far-atomic path. End-of-kernel release fence writes the dirty
// L2 lines back before k_fold reads them.
// ---------------------------------------------------------------------------
__global__ void k_exp_scatter_xcd(float* __restrict__ w,
                                  const int* __restrict__ gsrc,
                                  const float* __restrict__ params,
                                  float* __restrict__ denomR,
                                  int N, int E) {
    float scale = params[0];
    float shift = params[1];
    float* dr = denomR + (size_t)xcc_id() * N;
    for (int e = blockIdx.x * blockDim.x + threadIdx.x; e < E;
         e += gridDim.x * blockDim.x) {
        float v = __expf(fmaf(w[e], scale, shift));
        w[e] = v;
        __hip_atomic_fetch_add(&dr[gsrc[e]], v,
                               __ATOMIC_RELAXED, __HIP_MEMORY_SCOPE_WORKGROUP);
    }
}

// Fallback (agent-scope atomics) if ws can't hold NUM_XCD replicas.
__global__ void k_exp_scatter_agent(float* __restrict__ w,
                                    const int* __restrict__ gsrc,
                                    const float* __restrict__ params,
                                    float* __restrict__ denom,
                                    int E) {
    float scale = params[0];
    float shift = params[1];
    for (int e = blockIdx.x * blockDim.x + threadIdx.x; e < E;
         e += gridDim.x * blockDim.x) {
        float v = __expf(fmaf(w[e], scale, shift));
        w[e] = v;
        atomicAdd(&denom[gsrc[e]], v);
    }
}

// ---------------------------------------------------------------------------
// K3b: fold replicas: denom[n] = sum_r denomR[r][n]
// ---------------------------------------------------------------------------
__global__ void k_fold(const float* __restrict__ denomR,
                       float* __restrict__ denom, int N, int R) {
    int n = blockIdx.x * blockDim.x + threadIdx.x;
    if (n < N) {
        float s = 0.f;
        for (int r = 0; r < R; ++r) s += denomR[(size_t)r * N + n];
        denom[n] = s;
    }
}

// ---------------------------------------------------------------------------
// K4: out[e] = w[e] / (1e-12 + denom[gsrc[e]])
// ---------------------------------------------------------------------------
__global__ void k_normalize(const float* __restrict__ w,
                            const int* __restrict__ gsrc,
                            const float* __restrict__ denom,
                            float* __restrict__ out,
                            int E) {
    for (int e = blockIdx.x * blockDim.x + threadIdx.x; e < E;
         e += gridDim.x * blockDim.x) {
        out[e] = w[e] / (1e-12f + denom[gsrc[e]]);
    }
}

extern "C" void kernel_launch(void* const* d_in, const int* in_sizes, int n_in,
                              void* d_out, int out_size, void* d_ws, size_t ws_size,
                              hipStream_t stream) {
    const float* src_emb = (const float*)d_in[0];
    const float* dst_emb = (const float*)d_in[1];
    const float* bnw     = (const float*)d_in[2];
    const float* bnb     = (const float*)d_in[3];
    const int*   gsrc    = (const int*)d_in[4];
    const int*   gdst    = (const int*)d_in[5];

    const int E = in_sizes[4];           // 3,200,000 edges
    const int N = in_sizes[0] / 12;      // 100,000 nodes
    float* out = (float*)d_out;

    // workspace layout:
    //   [0,16)          double acc[2]
    //   [16,32)         float params[2]
    //   [32, 32+4E)     like / w
    //   then            denom fold target (N floats)
    //   then            denomR (NUM_XCD * N floats)
    char* ws = (char*)d_ws;
    double* acc    = (double*)ws;
    float*  params = (float*)(ws + 16);
    float*  like   = (float*)(ws + 32);
    float*  denom  = (float*)(ws + 32 + (size_t)E * 4);
    float*  denomR = denom + N;

    size_t need_xcd = 32 + (size_t)E * 4 + (size_t)N * 4 * (1 + NUM_XCD);
    bool xcd_mode = (ws_size >= need_xcd);

    const int block = 256;
    const int blocks = min((E + block - 1) / block, 4096);

    hipMemsetAsync(ws, 0, 32, stream);

    k_dot_stats<<<blocks, block, 0, stream>>>(src_emb, dst_emb, gsrc, gdst,
                                              like, acc, E);
    k_params<<<1, 1, 0, stream>>>(acc, bnw, bnb, params, E);

    if (xcd_mode) {
        hipMemsetAsync(denomR, 0, (size_t)NUM_XCD * N * 4, stream);
        k_exp_scatter_xcd<<<blocks, block, 0, stream>>>(like, gsrc, params,
                                                        denomR, N, E);
        k_fold<<<(N + block - 1) / block, block, 0, stream>>>(denomR, denom,
                                                              N, NUM_XCD);
    } else {
        hipMemsetAsync(denom, 0, (size_t)N * 4, stream);
        k_exp_scatter_agent<<<blocks, block, 0, stream>>>(like, gsrc, params,
                                                          denom, E);
    }

    k_normalize<<<blocks, block, 0, stream>>>(like, gsrc, denom, out, E);
}

// Round 4
// 208.319 us; speedup vs baseline: 1.5722x; 1.5480x over previous
//
#include <hip/hip_runtime.h>
#include <hip/hip_bf16.h>

#define BN_EPS 1e-5f
#define BUCKET 16000   // nodes per bucket -> 64,000 B static LDS (safe size)

// ---------------------------------------------------------------------------
// K1: per-edge dot product + block-reduced sum/sumsq into double accumulators.
// ---------------------------------------------------------------------------
__global__ void k_dot_stats(const float* __restrict__ src_emb,
                            const float* __restrict__ dst_emb,
                            const int* __restrict__ gsrc,
                            const int* __restrict__ gdst,
                            float* __restrict__ like,
                            double* __restrict__ acc,   // acc[0]=sum, acc[1]=sumsq
                            int E) {
    float lsum = 0.f, lsq = 0.f;
    for (int e = blockIdx.x * blockDim.x + threadIdx.x; e < E;
         e += gridDim.x * blockDim.x) {
        int s = gsrc[e];
        int d = gdst[e];
        const float4* a = (const float4*)(src_emb + (size_t)s * 12);
        const float4* b = (const float4*)(dst_emb + (size_t)d * 12);
        float4 a0 = a[0], a1 = a[1], a2 = a[2];
        float4 b0 = b[0], b1 = b[1], b2 = b[2];
        float dot = a0.x * b0.x + a0.y * b0.y + a0.z * b0.z + a0.w * b0.w
                  + a1.x * b1.x + a1.y * b1.y + a1.z * b1.z + a1.w * b1.w
                  + a2.x * b2.x + a2.y * b2.y + a2.z * b2.z + a2.w * b2.w;
        like[e] = dot;
        lsum += dot;
        lsq  += dot * dot;
    }
    for (int off = 32; off > 0; off >>= 1) {
        lsum += __shfl_down(lsum, off);
        lsq  += __shfl_down(lsq, off);
    }
    __shared__ float ssum[8], ssq[8];
    int wave = threadIdx.x >> 6;
    int lane = threadIdx.x & 63;
    if (lane == 0) { ssum[wave] = lsum; ssq[wave] = lsq; }
    __syncthreads();
    if (threadIdx.x == 0) {
        float ts = 0.f, tq = 0.f;
        int nw = blockDim.x >> 6;
        for (int i = 0; i < nw; ++i) { ts += ssum[i]; tq += ssq[i]; }
        atomicAdd(&acc[0], (double)ts);
        atomicAdd(&acc[1], (double)tq);
    }
}

// ---------------------------------------------------------------------------
// K2: fold batch stats + bn affine into (scale, shift).
// ---------------------------------------------------------------------------
__global__ void k_params(const double* __restrict__ acc,
                         const float* __restrict__ bnw,
                         const float* __restrict__ bnb,
                         float* __restrict__ params,
                         int E) {
    double mean = acc[0] / (double)E;
    double var  = acc[1] / (double)E - mean * mean;
    float invstd = rsqrtf((float)var + BN_EPS);
    float scale = bnw[0] * invstd;
    params[0] = scale;
    params[1] = bnb[0] - (float)mean * scale;
}

// ---------------------------------------------------------------------------
// K3: LDS-privatized segment sum. Block (g, p): stream edge slice g, keep an
// LDS accumulator for node bucket p, emit one private slab (no global
// atomics). v = exp(like*scale+shift) is recomputed on the fly (cheaper than
// a 25.6 MB w round-trip).
// ---------------------------------------------------------------------------
__global__ __launch_bounds__(512) void k_bucket_scatter(
        const float* __restrict__ like,
        const int* __restrict__ gsrc,
        const float* __restrict__ params,
        float* __restrict__ slab,   // [(p*G + g) * BUCKET]
        int E, int G) {
    __shared__ float sm[BUCKET];
    const int g  = blockIdx.x;
    const int p  = blockIdx.y;
    const int lo = p * BUCKET;

    for (int i = threadIdx.x; i < BUCKET; i += blockDim.x) sm[i] = 0.f;
    __syncthreads();

    const float scale = params[0];
    const float shift = params[1];

    // edge slice [s0, s1), s0 multiple of 4
    int per = (E + G - 1) / G;
    per = (per + 3) & ~3;
    const int s0 = g * per;
    const int s1 = min(s0 + per, E);

    for (int e = s0 + (int)threadIdx.x * 4; e < s1; e += (int)blockDim.x * 4) {
        if (e + 4 <= s1) {
            int4   n4 = *(const int4*)(gsrc + e);
            float4 l4 = *(const float4*)(like + e);
            unsigned o0 = (unsigned)(n4.x - lo);
            unsigned o1 = (unsigned)(n4.y - lo);
            unsigned o2 = (unsigned)(n4.z - lo);
            unsigned o3 = (unsigned)(n4.w - lo);
            if (o0 < BUCKET) atomicAdd(&sm[o0], __expf(fmaf(l4.x, scale, shift)));
            if (o1 < BUCKET) atomicAdd(&sm[o1], __expf(fmaf(l4.y, scale, shift)));
            if (o2 < BUCKET) atomicAdd(&sm[o2], __expf(fmaf(l4.z, scale, shift)));
            if (o3 < BUCKET) atomicAdd(&sm[o3], __expf(fmaf(l4.w, scale, shift)));
        } else {
            for (int k = 0; e + k < s1; ++k) {
                unsigned o = (unsigned)(gsrc[e + k] - lo);
                if (o < BUCKET)
                    atomicAdd(&sm[o], __expf(fmaf(like[e + k], scale, shift)));
            }
        }
    }
    __syncthreads();

    float* dst = slab + ((size_t)p * G + g) * BUCKET;
    for (int i = threadIdx.x; i < BUCKET; i += blockDim.x) dst[i] = sm[i];
}

// ---------------------------------------------------------------------------
// K3b: fold slabs: denom[n] = sum_g slab[(p(n)*G + g)*BUCKET + n%BUCKET]
// ---------------------------------------------------------------------------
__global__ void k_fold(const float* __restrict__ slab,
                       float* __restrict__ denom, int N, int G) {
    int n = blockIdx.x * blockDim.x + threadIdx.x;
    if (n >= N) return;
    int p   = n / BUCKET;
    int off = n - p * BUCKET;
    const float* s = slab + (size_t)p * G * BUCKET + off;
    float acc = 0.f;
    for (int g = 0; g < G; ++g) acc += s[(size_t)g * BUCKET];
    denom[n] = acc;
}

// ---------------------------------------------------------------------------
// K4: out[e] = exp(like*scale+shift) / (1e-12 + denom[gsrc[e]]) (vectorized)
// ---------------------------------------------------------------------------
__global__ void k_normalize(const float* __restrict__ like,
                            const int* __restrict__ gsrc,
                            const float* __restrict__ params,
                            const float* __restrict__ denom,
                            float* __restrict__ out,
                            int E) {
    const float scale = params[0];
    const float shift = params[1];
    int e = (blockIdx.x * blockDim.x + threadIdx.x) * 4;
    if (e + 4 <= E) {
        int4   n4 = *(const int4*)(gsrc + e);
        float4 l4 = *(const float4*)(like + e);
        float4 o;
        o.x = __expf(fmaf(l4.x, scale, shift)) / (1e-12f + denom[n4.x]);
        o.y = __expf(fmaf(l4.y, scale, shift)) / (1e-12f + denom[n4.y]);
        o.z = __expf(fmaf(l4.z, scale, shift)) / (1e-12f + denom[n4.z]);
        o.w = __expf(fmaf(l4.w, scale, shift)) / (1e-12f + denom[n4.w]);
        *(float4*)(out + e) = o;
    } else {
        for (; e < E; ++e)
            out[e] = __expf(fmaf(like[e], scale, shift)) /
                     (1e-12f + denom[gsrc[e]]);
    }
}

// Fallback (agent-scope atomics) if ws can't hold the slab.
__global__ void k_exp_scatter_agent(const float* __restrict__ like,
                                    const int* __restrict__ gsrc,
                                    const float* __restrict__ params,
                                    float* __restrict__ denom,
                                    int E) {
    float scale = params[0];
    float shift = params[1];
    for (int e = blockIdx.x * blockDim.x + threadIdx.x; e < E;
         e += gridDim.x * blockDim.x) {
        atomicAdd(&denom[gsrc[e]], __expf(fmaf(like[e], scale, shift)));
    }
}

extern "C" void kernel_launch(void* const* d_in, const int* in_sizes, int n_in,
                              void* d_out, int out_size, void* d_ws, size_t ws_size,
                              hipStream_t stream) {
    const float* src_emb = (const float*)d_in[0];
    const float* dst_emb = (const float*)d_in[1];
    const float* bnw     = (const float*)d_in[2];
    const float* bnb     = (const float*)d_in[3];
    const int*   gsrc    = (const int*)d_in[4];
    const int*   gdst    = (const int*)d_in[5];

    const int E = in_sizes[4];           // 3,200,000 edges
    const int N = in_sizes[0] / 12;      // 100,000 nodes
    float* out = (float*)d_out;

    const int P = (N + BUCKET - 1) / BUCKET;   // node buckets

    // workspace layout:
    //   [0,16)    double acc[2]
    //   [16,32)   float params[2]
    //   [32,..)   like (E floats)
    //   then      denom (N floats)
    //   then      slab (P*G*BUCKET floats)
    char* ws = (char*)d_ws;
    double* acc    = (double*)ws;
    float*  params = (float*)(ws + 16);
    float*  like   = (float*)(ws + 32);
    float*  denom  = (float*)(ws + 32 + (size_t)E * 4);
    float*  slab   = denom + N;

    size_t fixed = 32 + (size_t)E * 4 + (size_t)N * 4;
    int G = 0;
    for (int cand = 64; cand >= 8; cand >>= 1) {
        if (fixed + (size_t)P * cand * BUCKET * 4 <= ws_size) { G = cand; break; }
    }

    const int block = 256;
    const int blocks = min((E + block - 1) / block, 4096);

    hipMemsetAsync(ws, 0, 32, stream);

    k_dot_stats<<<blocks, block, 0, stream>>>(src_emb, dst_emb, gsrc, gdst,
                                              like, acc, E);
    k_params<<<1, 1, 0, stream>>>(acc, bnw, bnb, params, E);

    if (G > 0) {
        dim3 grid(G, P);
        k_bucket_scatter<<<grid, 512, 0, stream>>>(like, gsrc, params, slab, E, G);
        k_fold<<<(N + block - 1) / block, block, 0, stream>>>(slab, denom, N, G);
    } else {
        hipMemsetAsync(denom, 0, (size_t)N * 4, stream);
        k_exp_scatter_agent<<<blocks, block, 0, stream>>>(like, gsrc, params,
                                                          denom, E);
    }

    k_normalize<<<(E / 4 + block - 1) / block, block, 0, stream>>>(
        like, gsrc, params, denom, out, E);
}

// Round 5
// 183.312 us; speedup vs baseline: 1.7866x; 1.1364x over previous
//
#include <hip/hip_runtime.h>
#include <hip/hip_fp16.h>

#define BN_EPS 1e-5f
#define BUCKET 16000   // nodes per bucket -> 64,000 B static LDS

// ---------------------------------------------------------------------------
// K0: pack f32 [N][12] rows into fp16 [N][16] (32 B rows, line-aligned,
// zero-padded). Halves gather footprint and kills line-straddling.
// ---------------------------------------------------------------------------
__global__ void k_pack_half(const float* __restrict__ emb,
                            __half2* __restrict__ hemb, int N) {
    int n = blockIdx.x * blockDim.x + threadIdx.x;
    if (n >= N) return;
    const float* r = emb + (size_t)n * 12;
    union { int4 v[2]; __half2 h[8]; } u;
    #pragma unroll
    for (int k = 0; k < 6; ++k) u.h[k] = __floats2half2_rn(r[2 * k], r[2 * k + 1]);
    u.h[6] = __floats2half2_rn(0.f, 0.f);
    u.h[7] = u.h[6];
    int4* dst = (int4*)(hemb + (size_t)n * 8);
    dst[0] = u.v[0];
    dst[1] = u.v[1];
}

__device__ __forceinline__ float rowdot(const int4* __restrict__ a,
                                        const int4* __restrict__ b) {
    union U { int4 v; __half2 h[4]; };
    U a0{a[0]}, a1{a[1]}, b0{b[0]}, b1{b[1]};
    float dot = 0.f;
    #pragma unroll
    for (int k = 0; k < 4; ++k) {
        float2 fa = __half22float2(a0.h[k]);
        float2 fb = __half22float2(b0.h[k]);
        dot = fmaf(fa.x, fb.x, dot);
        dot = fmaf(fa.y, fb.y, dot);
    }
    #pragma unroll
    for (int k = 0; k < 2; ++k) {
        float2 fa = __half22float2(a1.h[k]);
        float2 fb = __half22float2(b1.h[k]);
        dot = fmaf(fa.x, fb.x, dot);
        dot = fmaf(fa.y, fb.y, dot);
    }
    return dot;
}

// ---------------------------------------------------------------------------
// K1: 4 edges/thread: int4 index loads, 8 independent 32 B row gathers in
// flight, fp32 accumulation; block-reduced sum/sumsq -> double atomics.
// ---------------------------------------------------------------------------
__global__ __launch_bounds__(256) void k_dot_stats(
        const __half2* __restrict__ hs,
        const __half2* __restrict__ hd,
        const int* __restrict__ gsrc,
        const int* __restrict__ gdst,
        float* __restrict__ like,
        double* __restrict__ acc,   // acc[0]=sum, acc[1]=sumsq
        int E) {
    int e0 = (blockIdx.x * blockDim.x + threadIdx.x) * 4;
    float lsum = 0.f, lsq = 0.f;
    if (e0 + 4 <= E) {
        int4 s4 = *(const int4*)(gsrc + e0);
        int4 d4 = *(const int4*)(gdst + e0);
        float4 dv;
        dv.x = rowdot((const int4*)(hs + (size_t)s4.x * 8),
                      (const int4*)(hd + (size_t)d4.x * 8));
        dv.y = rowdot((const int4*)(hs + (size_t)s4.y * 8),
                      (const int4*)(hd + (size_t)d4.y * 8));
        dv.z = rowdot((const int4*)(hs + (size_t)s4.z * 8),
                      (const int4*)(hd + (size_t)d4.z * 8));
        dv.w = rowdot((const int4*)(hs + (size_t)s4.w * 8),
                      (const int4*)(hd + (size_t)d4.w * 8));
        *(float4*)(like + e0) = dv;
        lsum = dv.x + dv.y + dv.z + dv.w;
        lsq  = dv.x * dv.x + dv.y * dv.y + dv.z * dv.z + dv.w * dv.w;
    } else {
        for (int e = e0; e < E; ++e) {
            float d = rowdot((const int4*)(hs + (size_t)gsrc[e] * 8),
                             (const int4*)(hd + (size_t)gdst[e] * 8));
            like[e] = d;
            lsum += d;
            lsq  += d * d;
        }
    }
    for (int off = 32; off > 0; off >>= 1) {
        lsum += __shfl_down(lsum, off);
        lsq  += __shfl_down(lsq, off);
    }
    __shared__ float ssum[4], ssq[4];
    int wave = threadIdx.x >> 6;
    int lane = threadIdx.x & 63;
    if (lane == 0) { ssum[wave] = lsum; ssq[wave] = lsq; }
    __syncthreads();
    if (threadIdx.x == 0) {
        float ts = 0.f, tq = 0.f;
        for (int i = 0; i < 4; ++i) { ts += ssum[i]; tq += ssq[i]; }
        atomicAdd(&acc[0], (double)ts);
        atomicAdd(&acc[1], (double)tq);
    }
}

// ---------------------------------------------------------------------------
// K2: fold batch stats + bn affine into (scale, shift).
// ---------------------------------------------------------------------------
__global__ void k_params(const double* __restrict__ acc,
                         const float* __restrict__ bnw,
                         const float* __restrict__ bnb,
                         float* __restrict__ params,
                         int E) {
    double mean = acc[0] / (double)E;
    double var  = acc[1] / (double)E - mean * mean;
    float invstd = rsqrtf((float)var + BN_EPS);
    float scale = bnw[0] * invstd;
    params[0] = scale;
    params[1] = bnb[0] - (float)mean * scale;
}

// ---------------------------------------------------------------------------
// K3: LDS-privatized segment sum, slab output, no global atomics.
// ---------------------------------------------------------------------------
__global__ __launch_bounds__(512) void k_bucket_scatter(
        const float* __restrict__ like,
        const int* __restrict__ gsrc,
        const float* __restrict__ params,
        float* __restrict__ slab,   // [(p*G + g) * BUCKET]
        int E, int G) {
    __shared__ float sm[BUCKET];
    const int g  = blockIdx.x;
    const int p  = blockIdx.y;
    const int lo = p * BUCKET;

    for (int i = threadIdx.x; i < BUCKET; i += blockDim.x) sm[i] = 0.f;
    __syncthreads();

    const float scale = params[0];
    const float shift = params[1];

    int per = (E + G - 1) / G;
    per = (per + 3) & ~3;
    const int s0 = g * per;
    const int s1 = min(s0 + per, E);

    for (int e = s0 + (int)threadIdx.x * 4; e < s1; e += (int)blockDim.x * 4) {
        if (e + 4 <= s1) {
            int4   n4 = *(const int4*)(gsrc + e);
            float4 l4 = *(const float4*)(like + e);
            unsigned o0 = (unsigned)(n4.x - lo);
            unsigned o1 = (unsigned)(n4.y - lo);
            unsigned o2 = (unsigned)(n4.z - lo);
            unsigned o3 = (unsigned)(n4.w - lo);
            if (o0 < BUCKET) atomicAdd(&sm[o0], __expf(fmaf(l4.x, scale, shift)));
            if (o1 < BUCKET) atomicAdd(&sm[o1], __expf(fmaf(l4.y, scale, shift)));
            if (o2 < BUCKET) atomicAdd(&sm[o2], __expf(fmaf(l4.z, scale, shift)));
            if (o3 < BUCKET) atomicAdd(&sm[o3], __expf(fmaf(l4.w, scale, shift)));
        } else {
            for (int k = 0; e + k < s1; ++k) {
                unsigned o = (unsigned)(gsrc[e + k] - lo);
                if (o < BUCKET)
                    atomicAdd(&sm[o], __expf(fmaf(like[e + k], scale, shift)));
            }
        }
    }
    __syncthreads();

    float* dst = slab + ((size_t)p * G + g) * BUCKET;
    for (int i = threadIdx.x; i < BUCKET; i += blockDim.x) dst[i] = sm[i];
}

// ---------------------------------------------------------------------------
// K3b: fold slabs: denom[n] = sum_g slab[(p(n)*G + g)*BUCKET + n%BUCKET]
// ---------------------------------------------------------------------------
__global__ void k_fold(const float* __restrict__ slab,
                       float* __restrict__ denom, int N, int G) {
    int n = blockIdx.x * blockDim.x + threadIdx.x;
    if (n >= N) return;
    int p   = n / BUCKET;
    int off = n - p * BUCKET;
    const float* s = slab + (size_t)p * G * BUCKET + off;
    float acc = 0.f;
    for (int g = 0; g < G; ++g) acc += s[(size_t)g * BUCKET];
    denom[n] = acc;
}

// ---------------------------------------------------------------------------
// K4: out[e] = exp(like*scale+shift) / (1e-12 + denom[gsrc[e]]) (vectorized)
// ---------------------------------------------------------------------------
__global__ void k_normalize(const float* __restrict__ like,
                            const int* __restrict__ gsrc,
                            const float* __restrict__ params,
                            const float* __restrict__ denom,
                            float* __restrict__ out,
                            int E) {
    const float scale = params[0];
    const float shift = params[1];
    int e = (blockIdx.x * blockDim.x + threadIdx.x) * 4;
    if (e + 4 <= E) {
        int4   n4 = *(const int4*)(gsrc + e);
        float4 l4 = *(const float4*)(like + e);
        float4 o;
        o.x = __expf(fmaf(l4.x, scale, shift)) / (1e-12f + denom[n4.x]);
        o.y = __expf(fmaf(l4.y, scale, shift)) / (1e-12f + denom[n4.y]);
        o.z = __expf(fmaf(l4.z, scale, shift)) / (1e-12f + denom[n4.z]);
        o.w = __expf(fmaf(l4.w, scale, shift)) / (1e-12f + denom[n4.w]);
        *(float4*)(out + e) = o;
    } else {
        for (; e < E; ++e)
            out[e] = __expf(fmaf(like[e], scale, shift)) /
                     (1e-12f + denom[gsrc[e]]);
    }
}

// Fallback (agent-scope atomics) if ws can't hold the slab.
__global__ void k_exp_scatter_agent(const float* __restrict__ like,
                                    const int* __restrict__ gsrc,
                                    const float* __restrict__ params,
                                    float* __restrict__ denom,
                                    int E) {
    float scale = params[0];
    float shift = params[1];
    for (int e = blockIdx.x * blockDim.x + threadIdx.x; e < E;
         e += gridDim.x * blockDim.x) {
        atomicAdd(&denom[gsrc[e]], __expf(fmaf(like[e], scale, shift)));
    }
}

extern "C" void kernel_launch(void* const* d_in, const int* in_sizes, int n_in,
                              void* d_out, int out_size, void* d_ws, size_t ws_size,
                              hipStream_t stream) {
    const float* src_emb = (const float*)d_in[0];
    const float* dst_emb = (const float*)d_in[1];
    const float* bnw     = (const float*)d_in[2];
    const float* bnb     = (const float*)d_in[3];
    const int*   gsrc    = (const int*)d_in[4];
    const int*   gdst    = (const int*)d_in[5];

    const int E = in_sizes[4];           // 3,200,000 edges
    const int N = in_sizes[0] / 12;      // 100,000 nodes
    float* out = (float*)d_out;

    const int P = (N + BUCKET - 1) / BUCKET;   // node buckets

    // workspace layout (all regions 64B-aligned):
    //   acc(16) | params(16) | pad | like(4E) | denom(4N) | hs(32N) | hd(32N) | slab
    char* ws = (char*)d_ws;
    double*  acc    = (double*)ws;
    float*   params = (float*)(ws + 16);
    size_t   off    = 64;
    float*   like   = (float*)(ws + off);  off += ((size_t)E * 4 + 63) & ~(size_t)63;
    float*   denom  = (float*)(ws + off);  off += ((size_t)N * 4 + 63) & ~(size_t)63;
    __half2* hs     = (__half2*)(ws + off); off += ((size_t)N * 32 + 63) & ~(size_t)63;
    __half2* hd     = (__half2*)(ws + off); off += ((size_t)N * 32 + 63) & ~(size_t)63;
    float*   slab   = (float*)(ws + off);

    int G = 0;
    for (int cand = 64; cand >= 8; cand >>= 1) {
        if (off + (size_t)P * cand * BUCKET * 4 <= ws_size) { G = cand; break; }
    }

    const int block = 256;

    hipMemsetAsync(ws, 0, 32, stream);

    k_pack_half<<<(N + block - 1) / block, block, 0, stream>>>(src_emb, hs, N);
    k_pack_half<<<(N + block - 1) / block, block, 0, stream>>>(dst_emb, hd, N);

    int dot_blocks = (E / 4 + block - 1) / block + 1;
    k_dot_stats<<<dot_blocks, block, 0, stream>>>(hs, hd, gsrc, gdst,
                                                  like, acc, E);
    k_params<<<1, 1, 0, stream>>>(acc, bnw, bnb, params, E);

    if (G > 0) {
        dim3 grid(G, P);
        k_bucket_scatter<<<grid, 512, 0, stream>>>(like, gsrc, params, slab, E, G);
        k_fold<<<(N + block - 1) / block, block, 0, stream>>>(slab, denom, N, G);
    } else {
        hipMemsetAsync(denom, 0, (size_t)N * 4, stream);
        int blocks = min((E + block - 1) / block, 4096);
        k_exp_scatter_agent<<<blocks, block, 0, stream>>>(like, gsrc, params,
                                                          denom, E);
    }

    k_normalize<<<(E / 4 + block - 1) / block, block, 0, stream>>>(
        like, gsrc, params, denom, out, E);
}

// Round 6
// 181.550 us; speedup vs baseline: 1.8040x; 1.0097x over previous
//
#include <hip/hip_runtime.h>
#include <hip/hip_fp16.h>

#define BN_EPS 1e-5f

typedef int      v4i __attribute__((ext_vector_type(4)));
typedef unsigned v4u __attribute__((ext_vector_type(4)));
typedef unsigned v2u __attribute__((ext_vector_type(2)));
typedef float    v4f __attribute__((ext_vector_type(4)));

__device__ __forceinline__ __half2 u2h2(unsigned u) {
    union { unsigned u; __half2 h; } c; c.u = u; return c.h;
}
__device__ __forceinline__ unsigned h22u(__half2 h) {
    union { unsigned u; __half2 h; } c; c.h = h; return c.u;
}

// ---------------------------------------------------------------------------
// K0: pack f32 [N][12] rows into fp16 [N][16] (32 B rows, line-aligned,
// zero-padded). Normal (cached) stores: the dot kernel re-reads these.
// ---------------------------------------------------------------------------
__global__ void k_pack_half(const float* __restrict__ emb,
                            __half2* __restrict__ hemb, int N) {
    int n = blockIdx.x * blockDim.x + threadIdx.x;
    if (n >= N) return;
    const float* r = emb + (size_t)n * 12;
    union { int4 v[2]; __half2 h[8]; } u;
    #pragma unroll
    for (int k = 0; k < 6; ++k) u.h[k] = __floats2half2_rn(r[2 * k], r[2 * k + 1]);
    u.h[6] = __floats2half2_rn(0.f, 0.f);
    u.h[7] = u.h[6];
    int4* dst = (int4*)(hemb + (size_t)n * 8);
    dst[0] = u.v[0];
    dst[1] = u.v[1];
}

__device__ __forceinline__ float rowdot(const int4* __restrict__ a,
                                        const int4* __restrict__ b) {
    union U { int4 v; __half2 h[4]; };
    U a0{a[0]}, a1{a[1]}, b0{b[0]}, b1{b[1]};
    float dot = 0.f;
    #pragma unroll
    for (int k = 0; k < 4; ++k) {
        float2 fa = __half22float2(a0.h[k]);
        float2 fb = __half22float2(b0.h[k]);
        dot = fmaf(fa.x, fb.x, dot);
        dot = fmaf(fa.y, fb.y, dot);
    }
    #pragma unroll
    for (int k = 0; k < 2; ++k) {
        float2 fa = __half22float2(a1.h[k]);
        float2 fb = __half22float2(b1.h[k]);
        dot = fmaf(fa.x, fb.x, dot);
        dot = fmaf(fa.y, fb.y, dot);
    }
    return dot;
}

// ---------------------------------------------------------------------------
// K1: 8 edges/thread. NT loads for the index streams (don't pollute L2 --
// the fp16 tables need the L2), normal loads for the gathered rows,
// NT 16B store of 8 fp16 likelihoods. Stats accumulated in fp32 from the
// un-rounded dots.
// ---------------------------------------------------------------------------
__global__ __launch_bounds__(256) void k_dot_stats(
        const __half2* __restrict__ hs,
        const __half2* __restrict__ hd,
        const int* __restrict__ gsrc,
        const int* __restrict__ gdst,
        __half* __restrict__ like,
        double* __restrict__ acc,   // acc[0]=sum, acc[1]=sumsq
        int E) {
    int e0 = (blockIdx.x * blockDim.x + threadIdx.x) * 8;
    float lsum = 0.f, lsq = 0.f;
    if (e0 + 8 <= E) {
        v4i s0 = __builtin_nontemporal_load((const v4i*)(gsrc + e0));
        v4i s1 = __builtin_nontemporal_load((const v4i*)(gsrc + e0 + 4));
        v4i d0 = __builtin_nontemporal_load((const v4i*)(gdst + e0));
        v4i d1 = __builtin_nontemporal_load((const v4i*)(gdst + e0 + 4));
        int is[8] = {s0.x, s0.y, s0.z, s0.w, s1.x, s1.y, s1.z, s1.w};
        int id[8] = {d0.x, d0.y, d0.z, d0.w, d1.x, d1.y, d1.z, d1.w};
        float dv[8];
        #pragma unroll
        for (int k = 0; k < 8; ++k) {
            dv[k] = rowdot((const int4*)(hs + (size_t)is[k] * 8),
                           (const int4*)(hd + (size_t)id[k] * 8));
            lsum += dv[k];
            lsq  = fmaf(dv[k], dv[k], lsq);
        }
        v4u o;
        o.x = h22u(__floats2half2_rn(dv[0], dv[1]));
        o.y = h22u(__floats2half2_rn(dv[2], dv[3]));
        o.z = h22u(__floats2half2_rn(dv[4], dv[5]));
        o.w = h22u(__floats2half2_rn(dv[6], dv[7]));
        __builtin_nontemporal_store(o, (v4u*)(like + e0));
    } else {
        for (int e = e0; e < E; ++e) {
            float d = rowdot((const int4*)(hs + (size_t)gsrc[e] * 8),
                             (const int4*)(hd + (size_t)gdst[e] * 8));
            like[e] = __float2half(d);
            lsum += d;
            lsq  += d * d;
        }
    }
    for (int off = 32; off > 0; off >>= 1) {
        lsum += __shfl_down(lsum, off);
        lsq  += __shfl_down(lsq, off);
    }
    __shared__ float ssum[4], ssq[4];
    int wave = threadIdx.x >> 6;
    int lane = threadIdx.x & 63;
    if (lane == 0) { ssum[wave] = lsum; ssq[wave] = lsq; }
    __syncthreads();
    if (threadIdx.x == 0) {
        float ts = 0.f, tq = 0.f;
        for (int i = 0; i < 4; ++i) { ts += ssum[i]; tq += ssq[i]; }
        atomicAdd(&acc[0], (double)ts);
        atomicAdd(&acc[1], (double)tq);
    }
}

// ---------------------------------------------------------------------------
// K2: fold batch stats + bn affine into (scale, shift).
// ---------------------------------------------------------------------------
__global__ void k_params(const double* __restrict__ acc,
                         const float* __restrict__ bnw,
                         const float* __restrict__ bnb,
                         float* __restrict__ params,
                         int E) {
    double mean = acc[0] / (double)E;
    double var  = acc[1] / (double)E - mean * mean;
    float invstd = rsqrtf((float)var + BN_EPS);
    float scale = bnw[0] * invstd;
    params[0] = scale;
    params[1] = bnb[0] - (float)mean * scale;
}

// ---------------------------------------------------------------------------
// K3: LDS-privatized segment sum, dynamic-LDS bucket (100 KB -> P=4 passes),
// NT streaming loads, slab output via NT stores, no global atomics.
// ---------------------------------------------------------------------------
__global__ __launch_bounds__(512) void k_bucket_scatter(
        const __half* __restrict__ like,
        const int* __restrict__ gsrc,
        const float* __restrict__ params,
        float* __restrict__ slab,   // [(p*G + g) * bucket]
        int E, int G, int bucket) {
    extern __shared__ float sm[];
    const int g  = blockIdx.x;
    const int p  = blockIdx.y;
    const int lo = p * bucket;

    for (int i = threadIdx.x; i < bucket; i += blockDim.x) sm[i] = 0.f;
    __syncthreads();

    const float scale = params[0];
    const float shift = params[1];

    int per = (E + G - 1) / G;
    per = (per + 3) & ~3;
    const int s0 = g * per;
    const int s1 = min(s0 + per, E);

    for (int e = s0 + (int)threadIdx.x * 4; e < s1; e += (int)blockDim.x * 4) {
        if (e + 4 <= s1) {
            v4i n4 = __builtin_nontemporal_load((const v4i*)(gsrc + e));
            v2u l2 = __builtin_nontemporal_load((const v2u*)(like + e));
            float2 fa = __half22float2(u2h2(l2.x));
            float2 fb = __half22float2(u2h2(l2.y));
            unsigned o0 = (unsigned)(n4.x - lo);
            unsigned o1 = (unsigned)(n4.y - lo);
            unsigned o2 = (unsigned)(n4.z - lo);
            unsigned o3 = (unsigned)(n4.w - lo);
            if (o0 < (unsigned)bucket) atomicAdd(&sm[o0], __expf(fmaf(fa.x, scale, shift)));
            if (o1 < (unsigned)bucket) atomicAdd(&sm[o1], __expf(fmaf(fa.y, scale, shift)));
            if (o2 < (unsigned)bucket) atomicAdd(&sm[o2], __expf(fmaf(fb.x, scale, shift)));
            if (o3 < (unsigned)bucket) atomicAdd(&sm[o3], __expf(fmaf(fb.y, scale, shift)));
        } else {
            for (int k = 0; e + k < s1; ++k) {
                unsigned o = (unsigned)(gsrc[e + k] - lo);
                if (o < (unsigned)bucket)
                    atomicAdd(&sm[o], __expf(fmaf(__half2float(like[e + k]), scale, shift)));
            }
        }
    }
    __syncthreads();

    float* dst = slab + ((size_t)p * G + g) * bucket;
    for (int i = threadIdx.x; i < bucket; i += blockDim.x)
        __builtin_nontemporal_store(sm[i], dst + i);
}

// ---------------------------------------------------------------------------
// K3b: fold slabs: denom[n] = sum_g slab[(p(n)*G + g)*bucket + n%bucket]
// denom stored with normal (cached) stores: normalize gathers it.
// ---------------------------------------------------------------------------
__global__ void k_fold(const float* __restrict__ slab,
                       float* __restrict__ denom, int N, int G, int bucket) {
    int n = blockIdx.x * blockDim.x + threadIdx.x;
    if (n >= N) return;
    int p   = n / bucket;
    int off = n - p * bucket;
    const float* s = slab + (size_t)p * G * bucket + off;
    float acc = 0.f;
    for (int g = 0; g < G; ++g)
        acc += __builtin_nontemporal_load(s + (size_t)g * bucket);
    denom[n] = acc;
}

// ---------------------------------------------------------------------------
// K4: out[e] = exp(like*scale+shift) / (1e-12 + denom[gsrc[e]])
// ---------------------------------------------------------------------------
__global__ void k_normalize(const __half* __restrict__ like,
                            const int* __restrict__ gsrc,
                            const float* __restrict__ params,
                            const float* __restrict__ denom,
                            float* __restrict__ out,
                            int E) {
    const float scale = params[0];
    const float shift = params[1];
    int e = (blockIdx.x * blockDim.x + threadIdx.x) * 4;
    if (e + 4 <= E) {
        v4i n4 = __builtin_nontemporal_load((const v4i*)(gsrc + e));
        v2u l2 = __builtin_nontemporal_load((const v2u*)(like + e));
        float2 fa = __half22float2(u2h2(l2.x));
        float2 fb = __half22float2(u2h2(l2.y));
        v4f o;
        o.x = __expf(fmaf(fa.x, scale, shift)) / (1e-12f + denom[n4.x]);
        o.y = __expf(fmaf(fa.y, scale, shift)) / (1e-12f + denom[n4.y]);
        o.z = __expf(fmaf(fb.x, scale, shift)) / (1e-12f + denom[n4.z]);
        o.w = __expf(fmaf(fb.y, scale, shift)) / (1e-12f + denom[n4.w]);
        __builtin_nontemporal_store(o, (v4f*)(out + e));
    } else {
        for (; e < E; ++e)
            out[e] = __expf(fmaf(__half2float(like[e]), scale, shift)) /
                     (1e-12f + denom[gsrc[e]]);
    }
}

// Fallback (agent-scope atomics) if ws can't hold the slab.
__global__ void k_exp_scatter_agent(const __half* __restrict__ like,
                                    const int* __restrict__ gsrc,
                                    const float* __restrict__ params,
                                    float* __restrict__ denom,
                                    int E) {
    float scale = params[0];
    float shift = params[1];
    for (int e = blockIdx.x * blockDim.x + threadIdx.x; e < E;
         e += gridDim.x * blockDim.x) {
        atomicAdd(&denom[gsrc[e]],
                  __expf(fmaf(__half2float(like[e]), scale, shift)));
    }
}

extern "C" void kernel_launch(void* const* d_in, const int* in_sizes, int n_in,
                              void* d_out, int out_size, void* d_ws, size_t ws_size,
                              hipStream_t stream) {
    const float* src_emb = (const float*)d_in[0];
    const float* dst_emb = (const float*)d_in[1];
    const float* bnw     = (const float*)d_in[2];
    const float* bnb     = (const float*)d_in[3];
    const int*   gsrc    = (const int*)d_in[4];
    const int*   gdst    = (const int*)d_in[5];

    const int E = in_sizes[4];           // 3,200,000 edges
    const int N = in_sizes[0] / 12;      // 100,000 nodes
    float* out = (float*)d_out;

    const int bucket = 25000;            // 100 KB dynamic LDS (128 KB wg-LDS
                                         // is proven on gfx950)
    const int P = (N + bucket - 1) / bucket;   // 4 passes

    // workspace layout (64B-aligned regions):
    //   acc(16) | params(16) | pad | like(2E fp16) | denom(4N) | hs(32N) |
    //   hd(32N) | slab(P*G*bucket*4)
    char* ws = (char*)d_ws;
    double*  acc    = (double*)ws;
    float*   params = (float*)(ws + 16);
    size_t   off    = 64;
    __half*  like   = (__half*)(ws + off);  off += ((size_t)E * 2 + 63) & ~(size_t)63;
    float*   denom  = (float*)(ws + off);   off += ((size_t)N * 4 + 63) & ~(size_t)63;
    __half2* hs     = (__half2*)(ws + off); off += ((size_t)N * 32 + 63) & ~(size_t)63;
    __half2* hd     = (__half2*)(ws + off); off += ((size_t)N * 32 + 63) & ~(size_t)63;
    float*   slab   = (float*)(ws + off);

    int G = 0;
    for (int cand = 64; cand >= 8; cand >>= 1) {
        if (off + (size_t)P * cand * bucket * 4 <= ws_size) { G = cand; break; }
    }

    const int block = 256;

    hipMemsetAsync(ws, 0, 32, stream);

    k_pack_half<<<(N + block - 1) / block, block, 0, stream>>>(src_emb, hs, N);
    k_pack_half<<<(N + block - 1) / block, block, 0, stream>>>(dst_emb, hd, N);

    int dot_blocks = (E / 8 + block - 1) / block + 1;
    k_dot_stats<<<dot_blocks, block, 0, stream>>>(hs, hd, gsrc, gdst,
                                                  like, acc, E);
    k_params<<<1, 1, 0, stream>>>(acc, bnw, bnb, params, E);

    if (G > 0) {
        dim3 grid(G, P);
        k_bucket_scatter<<<grid, 512, (size_t)bucket * 4, stream>>>(
            like, gsrc, params, slab, E, G, bucket);
        k_fold<<<(N + block - 1) / block, block, 0, stream>>>(slab, denom, N,
                                                              G, bucket);
    } else {
        hipMemsetAsync(denom, 0, (size_t)N * 4, stream);
        int blocks = min((E + block - 1) / block, 4096);
        k_exp_scatter_agent<<<blocks, block, 0, stream>>>(like, gsrc, params,
                                                          denom, E);
    }

    k_normalize<<<(E / 4 + block - 1) / block, block, 0, stream>>>(
        like, gsrc, params, denom, out, E);
}